// Round 4
// baseline (253.596 us; speedup 1.0000x reference)
//
#include <hip/hip_runtime.h>
#include <hip/hip_bf16.h>

// VecLocal2d: x[320][32][32][32] f32, weight[32][32][64][288] f32, bias[10][64][1024] f32
// out[320][64][1024] f32.  Per (h,w): out[m,o] = sum_k patch[m,k]*W[o,k] + bias.
//
// R4: (a) prep kernel fuses x-transpose (xT2[yx][m][c] bf16) AND weight permute into
// MFMA-fragment-major wP[loc][kt][quad][o][c8] bf16 -> main has NO LDS and NO barriers:
// A(weight)- and B(patch)-fragments are direct wave-contiguous global loads.
// (b) MFMA operands swapped (A=weight, B=patch) so D's lane dim = m -> out_s[loc][o][m]
// stored as bf16 (half the intermediate traffic, 32B-contig lane segments).
// (c) outT transposes bf16 [loc][o][m] -> f32 out[mo][loc] with bias fused.

typedef __attribute__((ext_vector_type(8))) short short8;
typedef __attribute__((ext_vector_type(4))) float f32x4;
typedef __attribute__((ext_vector_type(4))) unsigned short ushort4b;

#define XT2_ELEMS 10485760                 // 1024 yx * 320 m * 32 c
#define ZSLAB_ELEMS 10240                  // 320*32 zero slab for OOB taps
#define WP_OFF_BYTES 20992000              // (XT2_ELEMS+ZSLAB_ELEMS)*2
#define OUTS_OFF_BYTES 58740736            // WP_OFF + 1024*18432*2

__device__ __forceinline__ unsigned short f2bf(float f) {
    __hip_bfloat16 b = __float2bfloat16(f);
    return __builtin_bit_cast(unsigned short, b);
}
__device__ __forceinline__ float bf2f(unsigned short u) {
    unsigned int v = ((unsigned int)u) << 16;
    return __builtin_bit_cast(float, v);
}

// ---- kernel 1: prep. blocks 0..2559: x[mc][yx] f32 -> xT2[yx][mc] bf16.
//                blocks 2560..3583: weight[loc] -> wP[loc] frag-major bf16.
__global__ __launch_bounds__(256) void VecLocal2d_prep(const float* __restrict__ x,
                                                       const float* __restrict__ wgt,
                                                       unsigned short* __restrict__ xT2,
                                                       unsigned short* __restrict__ wP) {
    __shared__ unsigned short lds[18432];
    const int b = blockIdx.x;
    const int t = threadIdx.x;
    if (b < 2560) {
        unsigned short (*tile)[68] = (unsigned short(*)[68])lds;
        if (b == 0) {  // zero slab for out-of-bounds patch taps
#pragma unroll
            for (int j = 0; j < 20; ++j)
                reinterpret_cast<unsigned int*>(xT2 + XT2_ELEMS)[t + j * 256] = 0u;
        }
        const int mcb = b >> 4;            // 160 tiles over mc
        const int yxb = b & 15;            // 16 tiles over yx
        const int g = t >> 4;
        const int l4 = (t & 15) * 4;
#pragma unroll
        for (int p = 0; p < 4; ++p) {
            const int ml = g + p * 16;
            const float4 v = *reinterpret_cast<const float4*>(
                x + (size_t)(mcb * 64 + ml) * 1024 + yxb * 64 + l4);
            ushort4b u;
            u.x = f2bf(v.x); u.y = f2bf(v.y); u.z = f2bf(v.z); u.w = f2bf(v.w);
            *reinterpret_cast<ushort4b*>(&tile[ml][l4]) = u;
        }
        __syncthreads();
#pragma unroll
        for (int p = 0; p < 4; ++p) {
            const int yl = g + p * 16;
            ushort4b u;
            u.x = tile[l4 + 0][yl];
            u.y = tile[l4 + 1][yl];
            u.z = tile[l4 + 2][yl];
            u.w = tile[l4 + 3][yl];
            *reinterpret_cast<ushort4b*>(xT2 + (size_t)(yxb * 64 + yl) * 10240 + mcb * 64 + l4) = u;
        }
    } else {
        const int loc = b - 2560;
        const float* wg = wgt + (size_t)loc * 18432;
        // scatter into frag order in LDS: lidx = ((r*4 + c/8)*64 + o)*8 + (c&7)
#pragma unroll
        for (int i = 0; i < 18; ++i) {
            const int f4i = t + i * 256;
            const float4 v = reinterpret_cast<const float4*>(wg)[f4i];
            const float vv[4] = {v.x, v.y, v.z, v.w};
#pragma unroll
            for (int e = 0; e < 4; ++e) {
                const int klin = f4i * 4 + e;          // o*288 + c*9 + r
                const int o = klin / 288;
                const int rem = klin - o * 288;
                const int c = rem / 9;
                const int r = rem - c * 9;
                lds[((r * 4 + (c >> 3)) * 64 + o) * 8 + (c & 7)] = f2bf(vv[e]);
            }
        }
        __syncthreads();
        unsigned short* wp = wP + (size_t)loc * 18432;
#pragma unroll
        for (int i = 0; i < 9; ++i) {
            const int idx = t + i * 256;               // ushort8 index
            *reinterpret_cast<short8*>(wp + idx * 8) =
                *reinterpret_cast<const short8*>(&lds[idx * 8]);
        }
    }
}

// ---- kernel 2: main GEMM per location. No LDS, no barriers.
// A = weight frag (wP, frag-major), B = patch frag (xT2). D: row=o(quad*4+r), col=m(l16).
__global__ __launch_bounds__(256, 4) void VecLocal2d_main(const unsigned short* __restrict__ xT2,
                                                          const unsigned short* __restrict__ wP,
                                                          unsigned short* __restrict__ out_s) {
    // XCD swizzle: neighbors in (h,w) share XCD for xT2 L2 reuse.
    const int bid = blockIdx.x;
    const int s = bid >> 7;
    const int hg = bid & 127;
    const int h = hg >> 2;
    const int w = ((hg & 3) << 3) | s;
    const int loc = h * 32 + w;

    const int tid = threadIdx.x;
    const int lane = tid & 63;
    const int wave = tid >> 6;
    const int quad = lane >> 4;
    const int l16 = lane & 15;
    const int wm = wave >> 1, wo = wave & 1;  // 2x2 waves over (m32-subtile, o32-subtile)

    // ---- A-fragments (weight): 18 direct b128 loads, persistent in VGPRs ----
    const unsigned short* wloc = wP + (size_t)loc * 18432;
    short8 bfr[2][9];
#pragma unroll
    for (int oi = 0; oi < 2; ++oi) {
        const int o = (wo * 2 + oi) * 16 + l16;
#pragma unroll
        for (int kt = 0; kt < 9; ++kt)
            bfr[oi][kt] = *reinterpret_cast<const short8*>(
                wloc + ((kt * 4 + quad) * 64 + o) * 8);
    }

    // ---- 9 neighbor base offsets (block-uniform); OOB -> zero slab ----
    int base[9];
#pragma unroll
    for (int dy = 0; dy < 3; ++dy)
#pragma unroll
        for (int dx = 0; dx < 3; ++dx) {
            const int y = h - 1 + dy;
            const int xc = w - 1 + dx;
            const bool valid = ((unsigned)y < 32u) && ((unsigned)xc < 32u);
            base[dy * 3 + dx] = valid ? (y * 32 + xc) * 10240 : XT2_ELEMS;
        }

    const int laneB = l16 * 32 + quad * 8;   // B-frag: lane=m within tile, quad=c-chunk
    unsigned short* os = out_s + (size_t)loc * 20480;

    for (int mt = 0; mt < 5; ++mt) {
        const int m0 = (mt * 64 + wm * 32) * 32 + laneB;
        f32x4 acc[2][2] = {};
#pragma unroll
        for (int kt = 0; kt < 9; ++kt) {
            const short8 p0 = *reinterpret_cast<const short8*>(xT2 + base[kt] + m0);
            const short8 p1 = *reinterpret_cast<const short8*>(xT2 + base[kt] + m0 + 512);
            acc[0][0] = __builtin_amdgcn_mfma_f32_16x16x32_bf16(bfr[0][kt], p0, acc[0][0], 0, 0, 0);
            acc[0][1] = __builtin_amdgcn_mfma_f32_16x16x32_bf16(bfr[0][kt], p1, acc[0][1], 0, 0, 0);
            acc[1][0] = __builtin_amdgcn_mfma_f32_16x16x32_bf16(bfr[1][kt], p0, acc[1][0], 0, 0, 0);
            acc[1][1] = __builtin_amdgcn_mfma_f32_16x16x32_bf16(bfr[1][kt], p1, acc[1][1], 0, 0, 0);
        }
        // D: row o = quad*4+r (within 16-tile), col m = l16. Store bf16 [loc][o][m].
#pragma unroll
        for (int oi = 0; oi < 2; ++oi)
#pragma unroll
            for (int mi = 0; mi < 2; ++mi) {
                const int m = mt * 64 + wm * 32 + mi * 16 + l16;
#pragma unroll
                for (int r = 0; r < 4; ++r) {
                    const int o = (wo * 2 + oi) * 16 + quad * 4 + r;
                    os[o * 320 + m] = f2bf(acc[oi][mi][r]);
                }
            }
    }
}

// ---- kernel 3: out_s[loc][o][m] bf16 -> out[(m*64+o)*1024+loc] f32, bias fused.
// Block = (o, mt64, loc64-tile); tile transpose through LDS.
__global__ __launch_bounds__(256) void VecLocal2d_outT(const unsigned short* __restrict__ out_s,
                                                       const float* __restrict__ bias,
                                                       float* __restrict__ out) {
    __shared__ float tile[64][68];
    const int b = blockIdx.x;
    const int o = b & 63;
    const int mtlt = b >> 6;        // 0..79
    const int mt = mtlt >> 4;       // 0..4
    const int lt = mtlt & 15;
    const int t = threadIdx.x;
    const int lr = t >> 2;          // loc-local row 0..63
    const int q = t & 3;            // m-quarter
    const unsigned short* src =
        out_s + (size_t)(lt * 64 + lr) * 20480 + o * 320 + mt * 64 + q * 16;
    const short8 v0 = *reinterpret_cast<const short8*>(src);
    const short8 v1 = *reinterpret_cast<const short8*>(src + 8);
#pragma unroll
    for (int j = 0; j < 8; ++j) {
        tile[q * 16 + j][lr] = bf2f((unsigned short)v0[j]);
        tile[q * 16 + 8 + j][lr] = bf2f((unsigned short)v1[j]);
    }
    __syncthreads();
    const int ml = t >> 2;          // m-local 0..63
    const int lq = t & 3;           // loc-quarter
    const int m = mt * 64 + ml;
    const int cat = m % 10;
    const float* bp = bias + ((size_t)(cat * 64 + o)) * 1024 + lt * 64 + lq * 16;
    float* op = out + ((size_t)(m * 64 + o)) * 1024 + lt * 64 + lq * 16;
#pragma unroll
    for (int j = 0; j < 4; ++j) {
        const float4 bv = *reinterpret_cast<const float4*>(bp + j * 4);
        float4 v;
        v.x = tile[ml][lq * 16 + j * 4 + 0] + bv.x;
        v.y = tile[ml][lq * 16 + j * 4 + 1] + bv.y;
        v.z = tile[ml][lq * 16 + j * 4 + 2] + bv.z;
        v.w = tile[ml][lq * 16 + j * 4 + 3] + bv.w;
        *reinterpret_cast<float4*>(op + j * 4) = v;
    }
}

extern "C" void kernel_launch(void* const* d_in, const int* in_sizes, int n_in,
                              void* d_out, int out_size, void* d_ws, size_t ws_size,
                              hipStream_t stream) {
    const float* x = (const float*)d_in[0];
    const float* wgt = (const float*)d_in[1];
    const float* bias = (const float*)d_in[2];
    float* out = (float*)d_out;
    unsigned short* xT2 = (unsigned short*)d_ws;                           // 21.0 MB (+slab)
    unsigned short* wP = (unsigned short*)((char*)d_ws + WP_OFF_BYTES);    // 37.7 MB
    unsigned short* out_s = (unsigned short*)((char*)d_ws + OUTS_OFF_BYTES); // 41.9 MB

    VecLocal2d_prep<<<3584, 256, 0, stream>>>(x, wgt, xT2, wP);
    VecLocal2d_main<<<1024, 256, 0, stream>>>(xT2, wP, out_s);
    VecLocal2d_outT<<<5120, 256, 0, stream>>>(out_s, bias, out);
}